// Round 3
// baseline (140.770 us; speedup 1.0000x reference)
//
#include <hip/hip_runtime.h>

// SimpleMHA2D: B=32, S=HW=1024, C=KV=1024, N=16, K=V=64, fp32.
//  K1: qk[c][n] = sum_k k_kernel[c][n*64+k]*q[n][k];  qb[n] = sum_k k_bias*q
//  K2: logits[b][n][s] = x[b,s,:] . qk[:,n] + qb[n]   (register-resident qk)
//  K3: per (b,n): m = max_s, e[b][s][n] = exp(l-m), l_sum
//  K4: wp[b][ch][n][c] = sum_{s in chunk} e[b][s][n]*x[b,s,c]
//  K5: out[b][n][v] = (sum_ch wp . vk[:, n*64+v]) / l_sum + vb[n*64+v]

// ---------------- K1: fold query into k_kernel ----------------
__global__ __launch_bounds__(256) void k_qk(const float* __restrict__ kk,
                                            const float* __restrict__ q,
                                            const float* __restrict__ kb,
                                            float* __restrict__ qk,
                                            float* __restrict__ qb) {
  const int gid = blockIdx.x * 256 + threadIdx.x;   // 16384 = 1024c * 16n
  const int c = gid >> 4, n = gid & 15;
  float a = 0.f;
#pragma unroll
  for (int k4 = 0; k4 < 64; k4 += 4) {
    const float4 kv = *(const float4*)(kk + (size_t)c * 1024 + n * 64 + k4);
    const float4 qv = *(const float4*)(q + n * 64 + k4);
    a += kv.x * qv.x + kv.y * qv.y + kv.z * qv.z + kv.w * qv.w;
  }
  qk[gid] = a;  // layout [c][n], gid == c*16+n
  if (blockIdx.x == 0 && threadIdx.x < 16) {
    float s = 0.f;
    for (int k = 0; k < 64; k++) s += kb[threadIdx.x * 64 + k] * q[threadIdx.x * 64 + k];
    qb[threadIdx.x] = s;
  }
}

// ---------------- K2: logits_t[b][n][s] = x . qk + qb ----------------
// Block: 256 thr (4 waves), 32 rows. Wave w owns c-quarter [w*256, w*256+256).
// Lane = (c_sub = lane>>4, n = lane&15); lane's c-set: qbase + 16j + 4*c_sub + e
// (j=0..15, e=0..3). qk for that set lives in 64 VGPRs, loaded once.
// Per row: 16 global b128 loads (4 lane-addrs span ONE 64B line -> broadcast
// merge), 64 FMA, shfl_xor(16,32) reduce over c_sub, LDS only for the
// 4-quarter cross-wave reduce.
__global__ __launch_bounds__(256) void k_logits(const float* __restrict__ x,
                                                const float* __restrict__ qk,
                                                const float* __restrict__ qb,
                                                float* __restrict__ lg) {
  __shared__ float part[4 * 32 * 16];  // [wave][row][n], 8 KB
  const int tid = threadIdx.x;
  const int lane = tid & 63;
  const int wid = __builtin_amdgcn_readfirstlane(tid >> 6);
  const int qbase = wid << 8;          // wave's c-quarter
  const int c_sub = lane >> 4, n = lane & 15;

  const int row0 = blockIdx.x * 32;    // 1024 blocks; rows stay within one b
  const int b = row0 >> 10, s0 = row0 & 1023;

  // preload qk slice: qreg[j][e] = qk[qbase + 16j + 4*c_sub + e][n]
  float qreg[16][4];
  {
    const float* qkp = qk + ((size_t)(qbase + c_sub * 4) * 16 + n);
#pragma unroll
    for (int j = 0; j < 16; ++j) {
      qreg[j][0] = qkp[j * 256];
      qreg[j][1] = qkp[j * 256 + 16];
      qreg[j][2] = qkp[j * 256 + 32];
      qreg[j][3] = qkp[j * 256 + 48];
    }
  }

  const float* xbase = x + (size_t)row0 * 1024 + qbase + c_sub * 4;
#pragma unroll 1
  for (int r = 0; r < 32; ++r) {
    const float* xr = xbase + (size_t)r * 1024;
    float4 xv[16];
#pragma unroll
    for (int j = 0; j < 16; ++j) xv[j] = *(const float4*)(xr + j * 16);
    float a = 0.f;
#pragma unroll
    for (int j = 0; j < 16; ++j) {
      a += xv[j].x * qreg[j][0];
      a += xv[j].y * qreg[j][1];
      a += xv[j].z * qreg[j][2];
      a += xv[j].w * qreg[j][3];
    }
    // reduce over c_sub (lanes l, l^16, l^32, l^48)
    a += __shfl_xor(a, 16);
    a += __shfl_xor(a, 32);
    if (lane < 16) part[(wid * 32 + r) * 16 + lane] = a;
  }
  __syncthreads();

  // cross-wave reduce + coalesced transposed write
#pragma unroll
  for (int f = tid; f < 512; f += 256) {
    const int nn = f >> 5, si = f & 31;
    const float s = part[(0 * 32 + si) * 16 + nn] + part[(1 * 32 + si) * 16 + nn] +
                    part[(2 * 32 + si) * 16 + nn] + part[(3 * 32 + si) * 16 + nn] + qb[nn];
    lg[(size_t)(b * 16 + nn) * 1024 + s0 + si] = s;
  }
}

// ---------------- K3: softmax stats + exp (transposed write) ----------------
__global__ __launch_bounds__(256) void k_softmax(const float* __restrict__ lg,
                                                 float* __restrict__ es,
                                                 float* __restrict__ lsum) {
  const int bi = blockIdx.x;  // b*16+n, 512 blocks
  const int b = bi >> 4, n = bi & 15;
  const int tid = threadIdx.x;
  __shared__ float red[256];

  const float4 lv = *(const float4*)(lg + (size_t)bi * 1024 + tid * 4);
  float lm = fmaxf(fmaxf(lv.x, lv.y), fmaxf(lv.z, lv.w));
  red[tid] = lm; __syncthreads();
  for (int off = 128; off; off >>= 1) {
    if (tid < off) red[tid] = fmaxf(red[tid], red[tid + off]);
    __syncthreads();
  }
  const float m = red[0];
  __syncthreads();

  const float e0 = __expf(lv.x - m), e1 = __expf(lv.y - m);
  const float e2 = __expf(lv.z - m), e3 = __expf(lv.w - m);
  red[tid] = (e0 + e1) + (e2 + e3); __syncthreads();
  for (int off = 128; off; off >>= 1) {
    if (tid < off) red[tid] += red[tid + off];
    __syncthreads();
  }
  if (tid == 0) lsum[bi] = red[0];

  const size_t eb = ((size_t)b * 1024 + tid * 4) * 16 + n;  // es[b][s][n]
  es[eb] = e0; es[eb + 16] = e1; es[eb + 32] = e2; es[eb + 48] = e3;
}

// ---------------- K4: wp[b][ch][n][c] = sum_s e*x ----------------
__global__ __launch_bounds__(1024) void k_wsum(const float* __restrict__ x,
                                               const float* __restrict__ es,
                                               float* __restrict__ wp) {
  const int b = blockIdx.x >> 3, ch = blockIdx.x & 7;  // 256 blocks
  const int tid = threadIdx.x;
  const int lane = tid & 63, wid = tid >> 6;
  const int q = wid & 3, sub = wid >> 2;  // c-quarter, s-subchunk
  __shared__ float wl[16 * 1024];  // 64 KB

  for (int i = tid; i < 16 * 1024; i += 1024) wl[i] = 0.f;
  __syncthreads();

  float acc[16][4];
#pragma unroll
  for (int n = 0; n < 16; n++)
#pragma unroll
    for (int k = 0; k < 4; k++) acc[n][k] = 0.f;

  const int c0 = q * 256 + lane;
  for (int si = 0; si < 32; si++) {
    const int s = ch * 128 + sub * 32 + si;
    const float* xp = x + (size_t)(b * 1024 + s) * 1024;
    const float xk0 = xp[c0], xk1 = xp[c0 + 64], xk2 = xp[c0 + 128], xk3 = xp[c0 + 192];
    float4 e4[4];
    const float4* ep = (const float4*)(es + (size_t)(b * 1024 + s) * 16);
#pragma unroll
    for (int j = 0; j < 4; j++) e4[j] = ep[j];
#pragma unroll
    for (int n = 0; n < 16; n++) {
      const float ev = ((const float*)e4)[n];
      acc[n][0] += ev * xk0; acc[n][1] += ev * xk1;
      acc[n][2] += ev * xk2; acc[n][3] += ev * xk3;
    }
  }

  // phased non-atomic LDS accumulate (deterministic; lane-consecutive -> conflict-free)
  for (int ph = 0; ph < 4; ph++) {
    if (sub == ph) {
#pragma unroll
      for (int n = 0; n < 16; n++) {
        wl[n * 1024 + c0]       += acc[n][0];
        wl[n * 1024 + c0 + 64]  += acc[n][1];
        wl[n * 1024 + c0 + 128] += acc[n][2];
        wl[n * 1024 + c0 + 192] += acc[n][3];
      }
    }
    __syncthreads();
  }

  float* wpb = wp + (size_t)blockIdx.x * 16384;
  for (int i = tid; i < 16384; i += 1024) wpb[i] = wl[i];
}

// ---------------- K5: out = (w . vk)/l + vb ----------------
__global__ __launch_bounds__(256) void k_out(const float* __restrict__ wp,
                                             const float* __restrict__ vk,
                                             const float* __restrict__ vb,
                                             const float* __restrict__ lsum,
                                             float* __restrict__ out) {
  const int bi = blockIdx.x;  // b*16+n, 512 blocks
  const int b = bi >> 4, n = bi & 15;
  const int tid = threadIdx.x;
  __shared__ float wrow[1024];
  __shared__ float red[4][64];

  float4 a4 = {0.f, 0.f, 0.f, 0.f};
#pragma unroll
  for (int ch = 0; ch < 8; ch++) {
    const float4 t = *(const float4*)(wp + ((size_t)(b * 8 + ch) * 16 + n) * 1024 + tid * 4);
    a4.x += t.x; a4.y += t.y; a4.z += t.z; a4.w += t.w;
  }
  *(float4*)&wrow[tid * 4] = a4;
  __syncthreads();

  const int v = tid & 63, cq = tid >> 6;
  float a = 0.f;
  const float* vkc = vk + n * 64 + v;
  for (int ci = 0; ci < 256; ci++) {
    const int c = cq * 256 + ci;
    a += wrow[c] * vkc[(size_t)c * 1024];
  }
  red[cq][v] = a;
  __syncthreads();
  if (tid < 64) {
    const float o = (red[0][tid] + red[1][tid] + red[2][tid] + red[3][tid]) / lsum[bi]
                    + vb[n * 64 + tid];
    out[(size_t)b * 1024 + n * 64 + tid] = o;
  }
}

extern "C" void kernel_launch(void* const* d_in, const int* in_sizes, int n_in,
                              void* d_out, int out_size, void* d_ws, size_t ws_size,
                              hipStream_t stream) {
  const float* x  = (const float*)d_in[0];  // key_value [32,32,32,1024]
  const float* q  = (const float*)d_in[1];  // query [1,1,16,64]
  const float* kk = (const float*)d_in[2];  // k_kernel [1024,1024]
  const float* kb = (const float*)d_in[3];  // k_bias [1024]
  const float* vk = (const float*)d_in[4];  // v_kernel [1024,1024]
  const float* vb = (const float*)d_in[5];  // v_bias [1024]
  float* out = (float*)d_out;               // [32,16,64] fp32

  float* f   = (float*)d_ws;
  float* qk  = f;            // 16384
  float* qb  = f + 16384;    // 16
  float* ls  = f + 16400;    // 512
  float* lg  = f + 32768;    // 524288  logits_t[b][n][s]
  float* es  = f + 557056;   // 524288  e[b][s][n]
  float* wp  = f + 1081344;  // 4194304 wp[b][ch][n][c]   (total ~21.1 MB)

  hipLaunchKernelGGL(k_qk,      dim3(64),   dim3(256),  0, stream, kk, q, kb, qk, qb);
  hipLaunchKernelGGL(k_logits,  dim3(1024), dim3(256),  0, stream, x, qk, qb, lg);
  hipLaunchKernelGGL(k_softmax, dim3(512),  dim3(256),  0, stream, lg, es, ls);
  hipLaunchKernelGGL(k_wsum,    dim3(256),  dim3(1024), 0, stream, x, es, wp);
  hipLaunchKernelGGL(k_out,     dim3(512),  dim3(256),  0, stream, wp, vk, vb, ls, out);
}

// Round 5
// 88.017 us; speedup vs baseline: 1.5994x; 1.5994x over previous
//
#include <hip/hip_runtime.h>

// SimpleMHA2D: B=32, S=HW=1024, C=KV=1024, N=16, K=V=64, fp32.
//  K1: qk[c][n] = sum_k k_kernel[c][n*64+k]*q[n][k];  qb[n] = sum_k k_bias*q
//  K2: logits[b][n][s] = x[b,s,:] . qk[:,n] + qb[n]   (LDS qk read-only; register fold tail)
//  K3: per (b,n): m = max_s, e[b][s][n] = exp(l-m), l_sum
//  K4: wp[b][ch][n][c] = sum_{s in chunk} e[b][s][n]*x[b,s,c]
//  K5: out[b][n][v] = (sum_ch wp . vk[:, n*64+v]) / l_sum + vb[n*64+v]

// ---------------- K1: fold query into k_kernel ----------------
__global__ __launch_bounds__(256) void k_qk(const float* __restrict__ kk,
                                            const float* __restrict__ q,
                                            const float* __restrict__ kb,
                                            float* __restrict__ qk,
                                            float* __restrict__ qb) {
  const int gid = blockIdx.x * 256 + threadIdx.x;   // 16384 = 1024c * 16n
  const int c = gid >> 4, n = gid & 15;
  float a = 0.f;
#pragma unroll
  for (int k4 = 0; k4 < 64; k4 += 4) {
    const float4 kv = *(const float4*)(kk + (size_t)c * 1024 + n * 64 + k4);
    const float4 qv = *(const float4*)(q + n * 64 + k4);
    a += kv.x * qv.x + kv.y * qv.y + kv.z * qv.z + kv.w * qv.w;
  }
  qk[gid] = a;  // layout [c][n], gid == c*16+n
  if (blockIdx.x == 0 && threadIdx.x < 16) {
    float s = 0.f;
    for (int k = 0; k < 64; k++) s += kb[threadIdx.x * 64 + k] * q[threadIdx.x * 64 + k];
    qb[threadIdx.x] = s;
  }
}

// ---------------- K2: logits_t[b][n][s] = x . qk + qb ----------------
// 1024 thr = 16 waves; wave owns 4 rows; lane owns c = st*64 + lane per step.
// qkt[nq][c][e] staged once (read-only afterwards; single barrier).
// Tail: register-only reduce-scatter butterfly (no LDS, no barriers).
__global__ __launch_bounds__(1024) void k_logits(const float* __restrict__ x,
                                                 const float* __restrict__ qk,
                                                 const float* __restrict__ qb,
                                                 float* __restrict__ lg) {
  __shared__ float qkt[16384];  // 64 KB, never written after staging
  const int tid = threadIdx.x;
  const int lane = tid & 63;
  const int wid = tid >> 6;

  // stage qk[c][n] -> qkt[nq][c][e]
#pragma unroll
  for (int it = 0; it < 4; ++it) {
    const int g = it * 1024 + tid;
    const float4 v = *(const float4*)(qk + (size_t)g * 4);
    *(float4*)&qkt[(g & 3) * 4096 + (g >> 2) * 4] = v;
  }
  __syncthreads();

  const int row0 = blockIdx.x * 64 + wid * 4;  // 512 blocks x 64 rows
  const float* xw = x + (size_t)row0 * 1024 + lane;

  float acc[4][16];
#pragma unroll
  for (int r = 0; r < 4; ++r)
#pragma unroll
    for (int n = 0; n < 16; ++n) acc[r][n] = 0.f;

  float xa[4], xb[4];
#pragma unroll
  for (int r = 0; r < 4; ++r) xa[r] = xw[(size_t)r * 1024];

#pragma unroll 1
  for (int st = 0; st < 16; st += 2) {
#pragma unroll
    for (int r = 0; r < 4; ++r) xb[r] = xw[(size_t)r * 1024 + (st + 1) * 64];
    {
      const int c4 = (st * 64 + lane) * 4;
#pragma unroll
      for (int nq = 0; nq < 4; ++nq) {
        const float4 qv = *(const float4*)&qkt[nq * 4096 + c4];
#pragma unroll
        for (int r = 0; r < 4; ++r) {
          acc[r][nq * 4 + 0] += xa[r] * qv.x;
          acc[r][nq * 4 + 1] += xa[r] * qv.y;
          acc[r][nq * 4 + 2] += xa[r] * qv.z;
          acc[r][nq * 4 + 3] += xa[r] * qv.w;
        }
      }
    }
    if (st + 2 < 16) {
#pragma unroll
      for (int r = 0; r < 4; ++r) xa[r] = xw[(size_t)r * 1024 + (st + 2) * 64];
    }
    {
      const int c4 = ((st + 1) * 64 + lane) * 4;
#pragma unroll
      for (int nq = 0; nq < 4; ++nq) {
        const float4 qv = *(const float4*)&qkt[nq * 4096 + c4];
#pragma unroll
        for (int r = 0; r < 4; ++r) {
          acc[r][nq * 4 + 0] += xb[r] * qv.x;
          acc[r][nq * 4 + 1] += xb[r] * qv.y;
          acc[r][nq * 4 + 2] += xb[r] * qv.z;
          acc[r][nq * 4 + 3] += xb[r] * qv.w;
        }
      }
    }
  }

  // Reduce-scatter fold over lane bits 0..3 (distributes n), then pure sums
  // over bits 4,5. After: lane l holds full logit for n = l&15, all 4 rows.
  const int b0 = lane & 1, b1 = (lane >> 1) & 1;
  const int b2 = (lane >> 2) & 1, b3 = (lane >> 3) & 1;
  float f[4];
#pragma unroll
  for (int r = 0; r < 4; ++r) {
    float u[8];
#pragma unroll
    for (int m = 0; m < 8; ++m) {
      const float keep = b0 ? acc[r][2 * m + 1] : acc[r][2 * m];
      const float give = b0 ? acc[r][2 * m]     : acc[r][2 * m + 1];
      u[m] = keep + __shfl_xor(give, 1);
    }
    float w[4];
#pragma unroll
    for (int p = 0; p < 4; ++p) {
      const float keep = b1 ? u[2 * p + 1] : u[2 * p];
      const float give = b1 ? u[2 * p]     : u[2 * p + 1];
      w[p] = keep + __shfl_xor(give, 2);
    }
    float z[2];
#pragma unroll
    for (int qq = 0; qq < 2; ++qq) {
      const float keep = b2 ? w[2 * qq + 1] : w[2 * qq];
      const float give = b2 ? w[2 * qq]     : w[2 * qq + 1];
      z[qq] = keep + __shfl_xor(give, 4);
    }
    {
      const float keep = b3 ? z[1] : z[0];
      const float give = b3 ? z[0] : z[1];
      float t = keep + __shfl_xor(give, 8);
      t += __shfl_xor(t, 16);
      t += __shfl_xor(t, 32);
      f[r] = t;
    }
  }
  const int rsel = lane >> 4;
  float val = (rsel == 0) ? f[0] : (rsel == 1) ? f[1] : (rsel == 2) ? f[2] : f[3];
  val += qb[lane & 15];
  const int b = blockIdx.x >> 4, s0 = (blockIdx.x & 15) * 64;
  lg[(size_t)(b * 16 + (lane & 15)) * 1024 + s0 + wid * 4 + rsel] = val;
}

// ---------------- K3: softmax stats + exp (transposed write) ----------------
__global__ __launch_bounds__(256) void k_softmax(const float* __restrict__ lg,
                                                 float* __restrict__ es,
                                                 float* __restrict__ lsum) {
  const int bi = blockIdx.x;  // b*16+n, 512 blocks
  const int b = bi >> 4, n = bi & 15;
  const int tid = threadIdx.x;
  __shared__ float red[256];

  const float4 lv = *(const float4*)(lg + (size_t)bi * 1024 + tid * 4);
  float lm = fmaxf(fmaxf(lv.x, lv.y), fmaxf(lv.z, lv.w));
  red[tid] = lm; __syncthreads();
  for (int off = 128; off; off >>= 1) {
    if (tid < off) red[tid] = fmaxf(red[tid], red[tid + off]);
    __syncthreads();
  }
  const float m = red[0];
  __syncthreads();

  const float e0 = __expf(lv.x - m), e1 = __expf(lv.y - m);
  const float e2 = __expf(lv.z - m), e3 = __expf(lv.w - m);
  red[tid] = (e0 + e1) + (e2 + e3); __syncthreads();
  for (int off = 128; off; off >>= 1) {
    if (tid < off) red[tid] += red[tid + off];
    __syncthreads();
  }
  if (tid == 0) lsum[bi] = red[0];

  const size_t eb = ((size_t)b * 1024 + tid * 4) * 16 + n;  // es[b][s][n]
  es[eb] = e0; es[eb + 16] = e1; es[eb + 32] = e2; es[eb + 48] = e3;
}

// ---------------- K4: wp[b][ch][n][c] = sum_s e*x ----------------
__global__ __launch_bounds__(1024) void k_wsum(const float* __restrict__ x,
                                               const float* __restrict__ es,
                                               float* __restrict__ wp) {
  const int b = blockIdx.x >> 3, ch = blockIdx.x & 7;  // 256 blocks
  const int tid = threadIdx.x;
  const int lane = tid & 63, wid = tid >> 6;
  const int q = wid & 3, sub = wid >> 2;  // c-quarter, s-subchunk
  __shared__ float wl[16 * 1024];  // 64 KB

  for (int i = tid; i < 16 * 1024; i += 1024) wl[i] = 0.f;
  __syncthreads();

  float acc[16][4];
#pragma unroll
  for (int n = 0; n < 16; n++)
#pragma unroll
    for (int k = 0; k < 4; k++) acc[n][k] = 0.f;

  const int c0 = q * 256 + lane;
  for (int si = 0; si < 32; si++) {
    const int s = ch * 128 + sub * 32 + si;
    const float* xp = x + (size_t)(b * 1024 + s) * 1024;
    const float xk0 = xp[c0], xk1 = xp[c0 + 64], xk2 = xp[c0 + 128], xk3 = xp[c0 + 192];
    float4 e4[4];
    const float4* ep = (const float4*)(es + (size_t)(b * 1024 + s) * 16);
#pragma unroll
    for (int j = 0; j < 4; j++) e4[j] = ep[j];
#pragma unroll
    for (int n = 0; n < 16; n++) {
      const float ev = ((const float*)e4)[n];
      acc[n][0] += ev * xk0; acc[n][1] += ev * xk1;
      acc[n][2] += ev * xk2; acc[n][3] += ev * xk3;
    }
  }

  // phased non-atomic LDS accumulate (deterministic; lane-consecutive -> conflict-free)
  for (int ph = 0; ph < 4; ph++) {
    if (sub == ph) {
#pragma unroll
      for (int n = 0; n < 16; n++) {
        wl[n * 1024 + c0]       += acc[n][0];
        wl[n * 1024 + c0 + 64]  += acc[n][1];
        wl[n * 1024 + c0 + 128] += acc[n][2];
        wl[n * 1024 + c0 + 192] += acc[n][3];
      }
    }
    __syncthreads();
  }

  float* wpb = wp + (size_t)blockIdx.x * 16384;
  for (int i = tid; i < 16384; i += 1024) wpb[i] = wl[i];
}

// ---------------- K5: out = (w . vk)/l + vb ----------------
__global__ __launch_bounds__(256) void k_out(const float* __restrict__ wp,
                                             const float* __restrict__ vk,
                                             const float* __restrict__ vb,
                                             const float* __restrict__ lsum,
                                             float* __restrict__ out) {
  const int bi = blockIdx.x;  // b*16+n, 512 blocks
  const int b = bi >> 4, n = bi & 15;
  const int tid = threadIdx.x;
  __shared__ float wrow[1024];
  __shared__ float red[4][64];

  float4 a4 = {0.f, 0.f, 0.f, 0.f};
#pragma unroll
  for (int ch = 0; ch < 8; ch++) {
    const float4 t = *(const float4*)(wp + ((size_t)(b * 8 + ch) * 16 + n) * 1024 + tid * 4);
    a4.x += t.x; a4.y += t.y; a4.z += t.z; a4.w += t.w;
  }
  *(float4*)&wrow[tid * 4] = a4;
  __syncthreads();

  const int v = tid & 63, cq = tid >> 6;
  float a = 0.f;
  const float* vkc = vk + n * 64 + v;
  for (int ci = 0; ci < 256; ci++) {
    const int c = cq * 256 + ci;
    a += wrow[c] * vkc[(size_t)c * 1024];
  }
  red[cq][v] = a;
  __syncthreads();
  if (tid < 64) {
    const float o = (red[0][tid] + red[1][tid] + red[2][tid] + red[3][tid]) / lsum[bi]
                    + vb[n * 64 + tid];
    out[(size_t)b * 1024 + n * 64 + tid] = o;
  }
}

extern "C" void kernel_launch(void* const* d_in, const int* in_sizes, int n_in,
                              void* d_out, int out_size, void* d_ws, size_t ws_size,
                              hipStream_t stream) {
  const float* x  = (const float*)d_in[0];  // key_value [32,32,32,1024]
  const float* q  = (const float*)d_in[1];  // query [1,1,16,64]
  const float* kk = (const float*)d_in[2];  // k_kernel [1024,1024]
  const float* kb = (const float*)d_in[3];  // k_bias [1024]
  const float* vk = (const float*)d_in[4];  // v_kernel [1024,1024]
  const float* vb = (const float*)d_in[5];  // v_bias [1024]
  float* out = (float*)d_out;               // [32,16,64] fp32

  float* f   = (float*)d_ws;
  float* qk  = f;            // 16384
  float* qb  = f + 16384;    // 16
  float* ls  = f + 16400;    // 512
  float* lg  = f + 32768;    // 524288  logits_t[b][n][s]
  float* es  = f + 557056;   // 524288  e[b][s][n]
  float* wp  = f + 1081344;  // 4194304 wp[b][ch][n][c]   (total ~21.1 MB)

  hipLaunchKernelGGL(k_qk,      dim3(64),   dim3(256),  0, stream, kk, q, kb, qk, qb);
  hipLaunchKernelGGL(k_logits,  dim3(512),  dim3(1024), 0, stream, x, qk, qb, lg);
  hipLaunchKernelGGL(k_softmax, dim3(512),  dim3(256),  0, stream, lg, es, ls);
  hipLaunchKernelGGL(k_wsum,    dim3(256),  dim3(1024), 0, stream, x, es, wp);
  hipLaunchKernelGGL(k_out,     dim3(512),  dim3(256),  0, stream, wp, vk, vb, ls, out);
}